// Round 2
// 711.394 us; speedup vs baseline: 1.0498x; 1.0498x over previous
//
#include <hip/hip_runtime.h>
#include <hip/hip_bf16.h>
#include <math.h>

// Problem constants
#define B_  64
#define T_  128
#define E_  300
#define H_  256      // hidden per direction
#define G4  1024     // 4*H
#define N2  2048     // both directions' gates
#define GG  512      // G = 2H
#define FH_ 256
#define NC_ 2
#define KP  320      // E padded to multiple of 32

typedef __attribute__((ext_vector_type(8))) short short8;
typedef __attribute__((ext_vector_type(4))) float f32x4;
typedef unsigned short ushort_t;
typedef unsigned long long u64;

static __device__ __forceinline__ ushort_t bf16bits(float x) {
    __hip_bfloat16 b = __float2bfloat16(x);
    return __builtin_bit_cast(ushort_t, b);
}
static __device__ __forceinline__ float bf16lo(unsigned v) {
    return __builtin_bit_cast(float, v << 16);
}
static __device__ __forceinline__ float bf16hi(unsigned v) {
    return __builtin_bit_cast(float, v & 0xffff0000u);
}

// Fast sigmoid / tanh on the serial publish path (v_exp_f32 + v_rcp_f32).
static __device__ __forceinline__ float sigm_f(float x) {
    return __fdividef(1.f, 1.f + __expf(-x));
}
static __device__ __forceinline__ float tanh_f(float x) {
    return 1.f - __fdividef(2.f, __expf(2.f * x) + 1.f);
}

// 8 tagged-word loads, L1-bypassed, L2-SERVED (sc0 only). Used ONLY against
// hbufA, which is written with PLAIN stores (write-through L1 -> producer's
// XCD L2). When producer and consumer share an XCD this is a fully coherent
// L2-level exchange (~300cy RT). When they don't, the consumer's L2 holds a
// stale clean copy -> tag never matches -> sticky fallback to the agent-scope
// path on hbufB. Correctness never depends on placement.
static __device__ __forceinline__ void ld8_sc0(const u64* p, u64 v[8]) {
    u64 r0, r1, r2, r3, r4, r5, r6, r7;
    asm volatile(
        "global_load_dwordx2 %0, %8, off sc0\n\t"
        "global_load_dwordx2 %1, %8, off offset:8 sc0\n\t"
        "global_load_dwordx2 %2, %8, off offset:16 sc0\n\t"
        "global_load_dwordx2 %3, %8, off offset:24 sc0\n\t"
        "global_load_dwordx2 %4, %8, off offset:32 sc0\n\t"
        "global_load_dwordx2 %5, %8, off offset:40 sc0\n\t"
        "global_load_dwordx2 %6, %8, off offset:48 sc0\n\t"
        "global_load_dwordx2 %7, %8, off offset:56 sc0\n\t"
        "s_waitcnt vmcnt(0)"
        : "=&v"(r0), "=&v"(r1), "=&v"(r2), "=&v"(r3),
          "=&v"(r4), "=&v"(r5), "=&v"(r6), "=&v"(r7)
        : "v"(p)
        : "memory");
    v[0] = r0; v[1] = r1; v[2] = r2; v[3] = r3;
    v[4] = r4; v[5] = r5; v[6] = r6; v[7] = r7;
}

// ---------------------------------------------------------------------------
// Workspace layout (bytes):
//   0        : hbufB u64[2 parity][8 group][16 batch][128 word]    = 262144
//   262144   : bias2 (2048 f32)                                    = 8192
//   524288   : wihshuf (128 ntile x 10 ks x 64 lane x 8) bf16      = 1310720
//   1835008  : hbufA u64[2][8][16][128]  (L2 fast-path mirror)     = 262144
//   2097152  : xemb  (8192 x 320) bf16                             = 5242880
//   8388608  : xprojb (8192 x 2048) bf16                           = 33554432
//   41943040 : S     (64 x 512) f32                                = 131072
// h-word: [tag:32 | h_odd:bf16 | h_even:bf16]. tag = step index of the h
// state. Harness poison 0xAAAAAAAA can never equal a tag (tags are 0..128).
// Both A and B carry identical words; A via plain stores (XCD-L2 visible),
// B via relaxed agent-scope atomics (IC visible, the proven round-0 path).
// ---------------------------------------------------------------------------
#define OFF_BIAS  262144
#define OFF_WIH   524288
#define OFF_A     1835008
#define OFF_XEMB  2097152
#define OFF_XPROJ 8388608
#define OFF_S     41943040

// ---------------------------------------------------------------------------
// K_prep: fused (a) zero parity-0 of BOTH h buffers, (b) bias2, (c) w_ih
// shuffle to B-frag order, (d) embedding gather -> xemb bf16.
// ---------------------------------------------------------------------------
__global__ __launch_bounds__(256) void k_prep(
    const int*   __restrict__ sentence,
    const float* __restrict__ glove,
    const float* __restrict__ w_ih_f,
    const float* __restrict__ w_ih_b,
    const float* __restrict__ b_ih_f, const float* __restrict__ b_hh_f,
    const float* __restrict__ b_ih_b, const float* __restrict__ b_hh_b,
    u64*         __restrict__ hbufB,
    u64*         __restrict__ hbufA,
    float*       __restrict__ bias2,
    ushort_t*    __restrict__ wihshuf,
    ushort_t*    __restrict__ xemb) {
    const int idx = blockIdx.x * 256 + threadIdx.x;   // 0..655359

    // (a) zero parity-0 h words (tag 0 = initial h state) in both buffers
    if (idx < 16384) { hbufB[idx] = 0ull; hbufA[idx] = 0ull; }

    // (b) bias2[n] = b_ih + b_hh
    if (idx < N2) {
        bias2[idx] = (idx < G4) ? (b_ih_f[idx] + b_hh_f[idx])
                                : (b_ih_b[idx - G4] + b_hh_b[idx - G4]);
    }

    // (c) w_ih shuffle: p in [0,81920)
    if (idx < 81920) {
        const int ntile = idx / 640;
        const int r     = idx % 640;
        const int ks    = r / 64;
        const int lane  = r % 64;
        const int n  = ntile * 16 + (lane & 15);
        const int k0 = ks * 32 + ((lane >> 4) << 3);
        const float* src = (n < G4) ? (w_ih_f + (size_t)n * E_)
                                    : (w_ih_b + (size_t)(n - G4) * E_);
        ushort_t o[8];
        #pragma unroll
        for (int j = 0; j < 8; ++j) {
            const int k = k0 + j;
            o[j] = (k < E_) ? bf16bits(src[k]) : (ushort_t)0;
        }
        uint4 pk;
        pk.x = (unsigned)o[0] | ((unsigned)o[1] << 16);
        pk.y = (unsigned)o[2] | ((unsigned)o[3] << 16);
        pk.z = (unsigned)o[4] | ((unsigned)o[5] << 16);
        pk.w = (unsigned)o[6] | ((unsigned)o[7] << 16);
        *(uint4*)(wihshuf + (size_t)idx * 8) = pk;
    }

    // (d) embedding gather -> xemb bf16 (all threads)
    {
        const int m  = idx / 80;
        const int c4 = (idx % 80) * 4;
        const float* row = glove + (size_t)sentence[m] * E_;
        ushort_t o[4];
        #pragma unroll
        for (int j = 0; j < 4; ++j) {
            const int k = c4 + j;
            o[j] = (k < E_) ? bf16bits(row[k]) : (ushort_t)0;
        }
        uint2 pk;
        pk.x = (unsigned)o[0] | ((unsigned)o[1] << 16);
        pk.y = (unsigned)o[2] | ((unsigned)o[3] << 16);
        *(uint2*)(xemb + (size_t)m * KP + c4) = pk;
    }
}

// ---------------------------------------------------------------------------
// K1: xproj GEMM via bf16 MFMA, LDS-free K-loop + LDS-transpose epilogue
// for coalesced 1KB stores. grid (128,16) x 256 threads.
// ---------------------------------------------------------------------------
__global__ __launch_bounds__(256) void k_xproj_mfma(
    const ushort_t* __restrict__ xemb,
    const ushort_t* __restrict__ wihshuf,
    const float*    __restrict__ bias2,
    ushort_t*       __restrict__ xprojb) {
    __shared__ ushort_t ct[4][16][136];   // per-wave C tile, row pad +8
    const int tid = threadIdx.x;
    const int wave = tid >> 6, lane = tid & 63;
    const int quad = lane >> 4, l15 = lane & 15;
    const int m0 = blockIdx.x * 64 + wave * 16;
    const ushort_t* ap = xemb + (size_t)(m0 + l15) * KP;
    const ushort_t* wp = wihshuf + (size_t)blockIdx.y * 40960 + lane * 8;

    f32x4 acc[8] = {};
    #pragma unroll
    for (int ks = 0; ks < 10; ++ks) {
        short8 af = *(const short8*)(ap + ks * 32 + quad * 8);
        #pragma unroll
        for (int j = 0; j < 8; ++j) {
            short8 bf = *(const short8*)(wp + (size_t)(j * 10 + ks) * 512);
            acc[j] = __builtin_amdgcn_mfma_f32_16x16x32_bf16(af, bf, acc[j], 0, 0, 0);
        }
    }
    // C layout: row m = quad*4 + r, col n = j*16 + l15 -> stage in LDS
    #pragma unroll
    for (int j = 0; j < 8; ++j) {
        const float bias = bias2[blockIdx.y * 128 + j * 16 + l15];
        #pragma unroll
        for (int r = 0; r < 4; ++r)
            ct[wave][quad * 4 + r][j * 16 + l15] = bf16bits(acc[j][r] + bias);
    }
    // coalesced store: instr i covers rows [i*4, i*4+4), 16 lanes x 16B per row
    #pragma unroll
    for (int i = 0; i < 4; ++i) {
        const int row = i * 4 + (lane >> 4);
        uint4 v = *(const uint4*)&ct[wave][row][l15 * 8];
        *(uint4*)(xprojb + (size_t)(m0 + row) * N2 + blockIdx.y * 128 + l15 * 8) = v;
    }
}

// ---------------------------------------------------------------------------
// K2: BiLSTM, W register-resident, 8-way gate split, TAG-IN-DATA sync.
// 64 blocks x 256 threads; group g = blockIdx&7 = (dir, 16-batch group);
// slice = blockIdx>>3 owns h cells [slice*32, slice*32+32).
// Exchange: every producer thread double-publishes its tagged h word:
//   plain store   -> hbufA  (lands in producer-XCD L2; coherent for
//                            co-resident consumers via sc0 reads)
//   agent atomic  -> hbufB  (IC-visible; placement-independent)
// Consumers (all 256 threads, 8 words each) poll A with sc0 loads; after
// 48 failed rounds the link goes sticky-slow onto agent-scope polls of B.
// Tag+payload share one atomic 8B word; parity-slot reuse safety as before
// (every block consumes ALL tag-t words before publishing t+1).
// ---------------------------------------------------------------------------
__global__ __launch_bounds__(256, 1) void k_lstm_sync(
    const ushort_t* __restrict__ xprojb,   // (64,128,2048) bf16
    const float*    __restrict__ w_hh_f,   // (1024,256) f32
    const float*    __restrict__ w_hh_b,
    const int*      __restrict__ text_len,
    u64*            __restrict__ hbufB,    // [2][8][16][128] tagged words
    u64*            __restrict__ hbufA,    // same layout, L2 mirror
    float*          __restrict__ S)        // (64,512)
{
    __shared__ ushort_t hl[16][264];       // staged h bf16 [batch][k]
    __shared__ float    gLDS[4 * 16 * 33]; // [gate][batch][cell+pad]

    const int tid   = threadIdx.x;
    const int g     = blockIdx.x & 7;
    const int slice = blockIdx.x >> 3;
    const int d     = g & 1;
    const int b0    = (g >> 1) * 16;
    const int j0    = slice * 32;
    const int wave  = tid >> 6, lane = tid & 63;
    const int quad  = lane >> 4, l15 = lane & 15;

    const float* whh = d ? w_hh_b : w_hh_f;
    u64* slabB0 = hbufB + (size_t)g * 2048;          // parity 0
    u64* slabB1 = hbufB + 16384 + (size_t)g * 2048;  // parity 1
    u64* slabA0 = hbufA + (size_t)g * 2048;
    u64* slabA1 = hbufA + 16384 + (size_t)g * 2048;

    // ---- preload W B-frags into registers (once) ----
    short8 wfrag[2][8];
    #pragma unroll
    for (int u = 0; u < 2; ++u) {
        const int n = wave * 256 + j0 + u * 16 + l15;
        #pragma unroll
        for (int ks = 0; ks < 8; ++ks) {
            const float* p = whh + (size_t)n * 256 + ks * 32 + quad * 8;
            float4 lo = *(const float4*)p;
            float4 hi = *(const float4*)(p + 4);
            short8 f;
            f[0] = (short)bf16bits(lo.x); f[1] = (short)bf16bits(lo.y);
            f[2] = (short)bf16bits(lo.z); f[3] = (short)bf16bits(lo.w);
            f[4] = (short)bf16bits(hi.x); f[5] = (short)bf16bits(hi.y);
            f[6] = (short)bf16bits(hi.z); f[7] = (short)bf16bits(hi.w);
            wfrag[u][ks] = f;
        }
    }

    // poll assignment: thread polls batch mb = tid>>4, words pp0..pp0+7
    // (pp0 = (tid&15)*8) -> all 8 words belong to ONE producer slice
    // (pp0>>4): per-link sticky fallback is clean.
    // producer assignment: batch mb, cells c0,c0+1; word wi.
    const int mb  = tid >> 4;
    const int pp0 = (tid & 15) * 8;
    const int wi  = mb * 128 + slice * 16 + (tid & 15);
    const int c0  = (tid & 15) * 2;
    const int lenm = text_len[b0 + mb];
    float cst0 = 0.f, cst1 = 0.f, s0 = 0.f, s1 = 0.f;
    bool slow = false;   // sticky per-link fallback flag

    for (int t = 0; t < T_; ++t) {
        const int tt = d ? (T_ - 1 - t) : t;
        // prefetch xproj (bf16) — independent of h
        const ushort_t* xp = xprojb +
            ((size_t)(b0 + mb) * T_ + tt) * N2 + d * G4 + j0;
        const unsigned vi = *(const unsigned*)(xp + c0);
        const unsigned vf = *(const unsigned*)(xp + 256 + c0);
        const unsigned vg = *(const unsigned*)(xp + 512 + c0);
        const unsigned vo = *(const unsigned*)(xp + 768 + c0);

        // ---- poll own 8 tagged h words: A fast (L2), B slow (agent) ----
        const u64* srcA = ((t & 1) ? slabA1 : slabA0) + mb * 128 + pp0;
        const u64* srcB = ((t & 1) ? slabB1 : slabB0) + mb * 128 + pp0;
        u64 v[8];
        bool need = true;
        if (!slow) {
            for (int tries = 0; tries < 48 && need; ++tries) {
                ld8_sc0(srcA, v);
                bool ok = true;
                #pragma unroll
                for (int i = 0; i < 8; ++i)
                    ok = ok && ((unsigned)(v[i] >> 32) == (unsigned)t);
                if (ok) need = false;
            }
            if (need) slow = true;   // link not L2-coherent -> agent path
        }
        if (need) {
            for (;;) {
                #pragma unroll
                for (int i = 0; i < 8; ++i)
                    v[i] = __hip_atomic_load(srcB + i, __ATOMIC_RELAXED,
                                             __HIP_MEMORY_SCOPE_AGENT);
                bool ok = true;
                #pragma unroll
                for (int i = 0; i < 8; ++i)
                    ok = ok && ((unsigned)(v[i] >> 32) == (unsigned)t);
                if (ok) break;
            }
        }
        // stage payload: 16 ushorts (32B) contiguous per thread
        {
            uint4 pk0, pk1;
            pk0.x = (unsigned)v[0]; pk0.y = (unsigned)v[1];
            pk0.z = (unsigned)v[2]; pk0.w = (unsigned)v[3];
            pk1.x = (unsigned)v[4]; pk1.y = (unsigned)v[5];
            pk1.z = (unsigned)v[6]; pk1.w = (unsigned)v[7];
            *(uint4*)&hl[mb][pp0 * 2]     = pk0;
            *(uint4*)&hl[mb][pp0 * 2 + 8] = pk1;
        }
        __syncthreads();   // B1: hl ready; also fences gLDS reuse

        // ---- all waves: A-frags from LDS, MFMA ----
        short8 af[8];
        #pragma unroll
        for (int ks = 0; ks < 8; ++ks)
            af[ks] = *(const short8*)&hl[l15][ks * 32 + quad * 8];
        f32x4 acc[2] = {};
        #pragma unroll
        for (int ks = 0; ks < 8; ++ks) {
            acc[0] = __builtin_amdgcn_mfma_f32_16x16x32_bf16(
                af[ks], wfrag[0][ks], acc[0], 0, 0, 0);
            acc[1] = __builtin_amdgcn_mfma_f32_16x16x32_bf16(
                af[ks], wfrag[1][ks], acc[1], 0, 0, 0);
        }
        // C layout: row(batch)=quad*4+r, col=l15
        #pragma unroll
        for (int u = 0; u < 2; ++u)
            #pragma unroll
            for (int r = 0; r < 4; ++r)
                gLDS[wave * 528 + (quad * 4 + r) * 33 + u * 16 + l15] = acc[u][r];
        __syncthreads();   // B2: gates ready; also fences hl reuse

        // ---- cell update for (mb, c0..c0+1) ----
        const int gb = mb * 33 + c0;
        const float gi0 = gLDS[gb],        gi1 = gLDS[gb + 1];
        const float gf0 = gLDS[528 + gb],  gf1 = gLDS[528 + gb + 1];
        const float gg0 = gLDS[1056 + gb], gg1 = gLDS[1056 + gb + 1];
        const float go0 = gLDS[1584 + gb], go1 = gLDS[1584 + gb + 1];
        const float i0 = sigm_f(bf16lo(vi) + gi0);
        const float i1 = sigm_f(bf16hi(vi) + gi1);
        const float f0 = sigm_f(bf16lo(vf) + gf0);
        const float f1 = sigm_f(bf16hi(vf) + gf1);
        const float gc0 = tanh_f(bf16lo(vg) + gg0);
        const float gc1 = tanh_f(bf16hi(vg) + gg1);
        const float o0 = sigm_f(bf16lo(vo) + go0);
        const float o1 = sigm_f(bf16hi(vo) + go1);
        cst0 = f0 * cst0 + i0 * gc0;
        cst1 = f1 * cst1 + i1 * gc1;
        const float h0 = o0 * tanh_f(cst0);
        const float h1 = o1 * tanh_f(cst1);
        if (tt < lenm) { s0 += h0; s1 += h1; }

        // publish h_{t+1}: tag+payload in ONE 8B word, double-published.
        const u64 word = ((u64)(unsigned)(t + 1) << 32) |
                         (u64)((unsigned)bf16bits(h0) |
                               ((unsigned)bf16bits(h1) << 16));
        u64* dstA = ((t & 1) ? slabA0 : slabA1) + wi;
        u64* dstB = ((t & 1) ? slabB0 : slabB1) + wi;
        *(volatile u64*)dstA = word;            // plain -> XCD L2 (fast path)
        __hip_atomic_store(dstB, word, __ATOMIC_RELAXED,
                           __HIP_MEMORY_SCOPE_AGENT);  // IC (fallback path)
    }

    float2 sv; sv.x = s0; sv.y = s1;
    *(float2*)(S + (size_t)(b0 + mb) * GG + d * H_ + j0 + c0) = sv;
}

// ---------------------------------------------------------------------------
// K3: head (unchanged).
// ---------------------------------------------------------------------------
__global__ __launch_bounds__(256) void k_head(
    const float* __restrict__ S,
    const int*   __restrict__ text_len,
    const float* __restrict__ gat_w, const float* __restrict__ gat_b,
    const float* __restrict__ fc1_w, const float* __restrict__ fc1_b,
    const float* __restrict__ fc2_w, const float* __restrict__ fc2_b,
    const float* __restrict__ fcf_w, const float* __restrict__ fcf_b,
    float* __restrict__ out)
{
    __shared__ float sb[GG];
    __shared__ float x1[GG];
    __shared__ float x2[FH_];
    __shared__ float x3[FH_];
    const int b = blockIdx.x, tid = threadIdx.x;
    sb[tid]       = S[(size_t)b * GG + tid];
    sb[tid + 256] = S[(size_t)b * GG + tid + 256];
    __syncthreads();
    const float lenf = (float)text_len[b];
    #pragma unroll
    for (int r = 0; r < 2; ++r) {
        const int n = tid + r * 256;
        float acc = gat_b[n] * lenf;
        const float* w = gat_w + (size_t)n * GG;
        for (int k = 0; k < GG; ++k) acc += sb[k] * w[k];
        x1[n] = fmaxf(acc, 0.f);
    }
    __syncthreads();
    {
        float acc = fc1_b[tid];
        const float* w = fc1_w + (size_t)tid * GG;
        for (int k = 0; k < GG; ++k) acc += x1[k] * w[k];
        x2[tid] = fmaxf(acc, 0.f);
    }
    __syncthreads();
    {
        float acc = fc2_b[tid];
        const float* w = fc2_w + (size_t)tid * FH_;
        for (int k = 0; k < FH_; ++k) acc += x2[k] * w[k];
        x3[tid] = fmaxf(acc, 0.f);
    }
    __syncthreads();
    if (tid < NC_) {
        float acc = fcf_b[tid];
        const float* w = fcf_w + (size_t)tid * FH_;
        for (int k = 0; k < FH_; ++k) acc += x3[k] * w[k];
        out[b * NC_ + tid] = acc;
    }
}

// ---------------------------------------------------------------------------
extern "C" void kernel_launch(void* const* d_in, const int* in_sizes, int n_in,
                              void* d_out, int out_size, void* d_ws, size_t ws_size,
                              hipStream_t stream) {
    const int*   sentence = (const int*)  d_in[0];
    const int*   text_len = (const int*)  d_in[4];
    const float* glove    = (const float*)d_in[10];
    const float* w_ih_f   = (const float*)d_in[11];
    const float* w_hh_f   = (const float*)d_in[12];
    const float* b_ih_f   = (const float*)d_in[13];
    const float* b_hh_f   = (const float*)d_in[14];
    const float* w_ih_b   = (const float*)d_in[15];
    const float* w_hh_b   = (const float*)d_in[16];
    const float* b_ih_b   = (const float*)d_in[17];
    const float* b_hh_b   = (const float*)d_in[18];
    const float* gat_w    = (const float*)d_in[19];
    const float* gat_b    = (const float*)d_in[20];
    const float* fc1_w    = (const float*)d_in[21];
    const float* fc1_b    = (const float*)d_in[22];
    const float* fc2_w    = (const float*)d_in[23];
    const float* fc2_b    = (const float*)d_in[24];
    const float* fcf_w    = (const float*)d_in[25];
    const float* fcf_b    = (const float*)d_in[26];
    float* out = (float*)d_out;

    char* ws = (char*)d_ws;
    u64*      hbufB   = (u64*)ws;
    float*    bias2   = (float*)(ws + OFF_BIAS);
    ushort_t* wihshuf = (ushort_t*)(ws + OFF_WIH);
    u64*      hbufA   = (u64*)(ws + OFF_A);
    ushort_t* xemb    = (ushort_t*)(ws + OFF_XEMB);
    ushort_t* xprojb  = (ushort_t*)(ws + OFF_XPROJ);
    float*    S       = (float*)(ws + OFF_S);

    k_prep<<<2560, 256, 0, stream>>>(sentence, glove, w_ih_f, w_ih_b,
                                     b_ih_f, b_hh_f, b_ih_b, b_hh_b,
                                     hbufB, hbufA, bias2, wihshuf, xemb);
    dim3 gx(128, 16);
    k_xproj_mfma<<<gx, 256, 0, stream>>>(xemb, wihshuf, bias2, xprojb);
    k_lstm_sync<<<64, 256, 0, stream>>>(xprojb, w_hh_f, w_hh_b, text_len,
                                        hbufB, hbufA, S);
    k_head<<<64, 256, 0, stream>>>(S, text_len, gat_w, gat_b,
                                   fc1_w, fc1_b, fc2_w, fc2_b,
                                   fcf_w, fcf_b, out);
}

// Round 3
// 710.670 us; speedup vs baseline: 1.0509x; 1.0010x over previous
//
#include <hip/hip_runtime.h>
#include <hip/hip_bf16.h>
#include <math.h>

// Problem constants
#define B_  64
#define T_  128
#define E_  300
#define H_  256      // hidden per direction
#define G4  1024     // 4*H
#define N2  2048     // both directions' gates
#define GG  512      // G = 2H
#define FH_ 256
#define NC_ 2
#define KP  320      // E padded to multiple of 32

typedef __attribute__((ext_vector_type(8))) short short8;
typedef __attribute__((ext_vector_type(4))) float f32x4;
typedef unsigned short ushort_t;
typedef unsigned long long u64;

static __device__ __forceinline__ ushort_t bf16bits(float x) {
    __hip_bfloat16 b = __float2bfloat16(x);
    return __builtin_bit_cast(ushort_t, b);
}
static __device__ __forceinline__ float bf16lo(unsigned v) {
    return __builtin_bit_cast(float, v << 16);
}
static __device__ __forceinline__ float bf16hi(unsigned v) {
    return __builtin_bit_cast(float, v & 0xffff0000u);
}

// Fast sigmoid / tanh on the serial publish path (v_exp_f32 + v_rcp_f32).
static __device__ __forceinline__ float sigm_f(float x) {
    return __fdividef(1.f, 1.f + __expf(-x));
}
static __device__ __forceinline__ float tanh_f(float x) {
    return 1.f - __fdividef(2.f, __expf(2.f * x) + 1.f);
}

// 8 tagged-word loads, L1-bypassed, L2-SERVED (sc0 only). Used ONLY against
// hbufA, which is written with PLAIN stores (write-through L1 -> producer's
// XCD L2). With the XCD role election below, a group's producers and
// consumers share one XCD L2, making this a coherent ~300cy exchange.
// Overflow (cross-XCD) links never match and go sticky to the agent path.
static __device__ __forceinline__ void ld8_sc0(const u64* p, u64 v[8]) {
    u64 r0, r1, r2, r3, r4, r5, r6, r7;
    asm volatile(
        "global_load_dwordx2 %0, %8, off sc0\n\t"
        "global_load_dwordx2 %1, %8, off offset:8 sc0\n\t"
        "global_load_dwordx2 %2, %8, off offset:16 sc0\n\t"
        "global_load_dwordx2 %3, %8, off offset:24 sc0\n\t"
        "global_load_dwordx2 %4, %8, off offset:32 sc0\n\t"
        "global_load_dwordx2 %5, %8, off offset:40 sc0\n\t"
        "global_load_dwordx2 %6, %8, off offset:48 sc0\n\t"
        "global_load_dwordx2 %7, %8, off offset:56 sc0\n\t"
        "s_waitcnt vmcnt(0)"
        : "=&v"(r0), "=&v"(r1), "=&v"(r2), "=&v"(r3),
          "=&v"(r4), "=&v"(r5), "=&v"(r6), "=&v"(r7)
        : "v"(p)
        : "memory");
    v[0] = r0; v[1] = r1; v[2] = r2; v[3] = r3;
    v[4] = r4; v[5] = r5; v[6] = r6; v[7] = r7;
}

// ---------------------------------------------------------------------------
// Workspace layout (bytes):
//   0        : hbufB u64[2 parity][8 group][16 batch][128 word]    = 262144
//   262144   : bias2 (2048 f32)                                    = 8192
//   270336   : ctl   (16 u32: [0..7] per-XCD count, [8] ovcnt,
//                     [9] grid barrier)                            = 64
//   524288   : wihshuf (128 ntile x 10 ks x 64 lane x 8) bf16      = 1310720
//   1835008  : hbufA u64[2][8][16][128]  (L2 fast-path mirror)     = 262144
//   2097152  : xemb  (8192 x 320) bf16                             = 5242880
//   8388608  : xprojb (8192 x 2048) bf16                           = 33554432
//   41943040 : S     (64 x 512) f32                                = 131072
// h-word: [tag:32 | h_odd:bf16 | h_even:bf16]. tag = step index of the h
// state. BOTH parities of both buffers are zeroed each launch: all stale
// tags are 0, which only ever matches the t=0 poll (parity 0), whose
// correct payload IS zero. This closes the cross-replay tag-127 race.
// ---------------------------------------------------------------------------
#define OFF_BIAS  262144
#define OFF_CTL   270336
#define OFF_WIH   524288
#define OFF_A     1835008
#define OFF_XEMB  2097152
#define OFF_XPROJ 8388608
#define OFF_S     41943040

// ---------------------------------------------------------------------------
// K_prep: fused (a) zero ALL parities of both h buffers + ctl, (b) bias2,
// (c) w_ih shuffle to B-frag order, (d) embedding gather -> xemb bf16.
// ---------------------------------------------------------------------------
__global__ __launch_bounds__(256) void k_prep(
    const int*   __restrict__ sentence,
    const float* __restrict__ glove,
    const float* __restrict__ w_ih_f,
    const float* __restrict__ w_ih_b,
    const float* __restrict__ b_ih_f, const float* __restrict__ b_hh_f,
    const float* __restrict__ b_ih_b, const float* __restrict__ b_hh_b,
    u64*         __restrict__ hbufB,
    u64*         __restrict__ hbufA,
    unsigned*    __restrict__ ctl,
    float*       __restrict__ bias2,
    ushort_t*    __restrict__ wihshuf,
    ushort_t*    __restrict__ xemb) {
    const int idx = blockIdx.x * 256 + threadIdx.x;   // 0..655359

    // (a) zero ALL h words (both parities, both buffers) + ctl
    if (idx < 32768) { hbufB[idx] = 0ull; hbufA[idx] = 0ull; }
    if (idx < 16) ctl[idx] = 0u;

    // (b) bias2[n] = b_ih + b_hh
    if (idx < N2) {
        bias2[idx] = (idx < G4) ? (b_ih_f[idx] + b_hh_f[idx])
                                : (b_ih_b[idx - G4] + b_hh_b[idx - G4]);
    }

    // (c) w_ih shuffle: p in [0,81920)
    if (idx < 81920) {
        const int ntile = idx / 640;
        const int r     = idx % 640;
        const int ks    = r / 64;
        const int lane  = r % 64;
        const int n  = ntile * 16 + (lane & 15);
        const int k0 = ks * 32 + ((lane >> 4) << 3);
        const float* src = (n < G4) ? (w_ih_f + (size_t)n * E_)
                                    : (w_ih_b + (size_t)(n - G4) * E_);
        ushort_t o[8];
        #pragma unroll
        for (int j = 0; j < 8; ++j) {
            const int k = k0 + j;
            o[j] = (k < E_) ? bf16bits(src[k]) : (ushort_t)0;
        }
        uint4 pk;
        pk.x = (unsigned)o[0] | ((unsigned)o[1] << 16);
        pk.y = (unsigned)o[2] | ((unsigned)o[3] << 16);
        pk.z = (unsigned)o[4] | ((unsigned)o[5] << 16);
        pk.w = (unsigned)o[6] | ((unsigned)o[7] << 16);
        *(uint4*)(wihshuf + (size_t)idx * 8) = pk;
    }

    // (d) embedding gather -> xemb bf16 (all threads)
    {
        const int m  = idx / 80;
        const int c4 = (idx % 80) * 4;
        const float* row = glove + (size_t)sentence[m] * E_;
        ushort_t o[4];
        #pragma unroll
        for (int j = 0; j < 4; ++j) {
            const int k = c4 + j;
            o[j] = (k < E_) ? bf16bits(row[k]) : (ushort_t)0;
        }
        uint2 pk;
        pk.x = (unsigned)o[0] | ((unsigned)o[1] << 16);
        pk.y = (unsigned)o[2] | ((unsigned)o[3] << 16);
        *(uint2*)(xemb + (size_t)m * KP + c4) = pk;
    }
}

// ---------------------------------------------------------------------------
// K1: xproj GEMM via bf16 MFMA, LDS-free K-loop + LDS-transpose epilogue
// for coalesced 1KB stores. grid (128,16) x 256 threads.
// ---------------------------------------------------------------------------
__global__ __launch_bounds__(256) void k_xproj_mfma(
    const ushort_t* __restrict__ xemb,
    const ushort_t* __restrict__ wihshuf,
    const float*    __restrict__ bias2,
    ushort_t*       __restrict__ xprojb) {
    __shared__ ushort_t ct[4][16][136];   // per-wave C tile, row pad +8
    const int tid = threadIdx.x;
    const int wave = tid >> 6, lane = tid & 63;
    const int quad = lane >> 4, l15 = lane & 15;
    const int m0 = blockIdx.x * 64 + wave * 16;
    const ushort_t* ap = xemb + (size_t)(m0 + l15) * KP;
    const ushort_t* wp = wihshuf + (size_t)blockIdx.y * 40960 + lane * 8;

    f32x4 acc[8] = {};
    #pragma unroll
    for (int ks = 0; ks < 10; ++ks) {
        short8 af = *(const short8*)(ap + ks * 32 + quad * 8);
        #pragma unroll
        for (int j = 0; j < 8; ++j) {
            short8 bf = *(const short8*)(wp + (size_t)(j * 10 + ks) * 512);
            acc[j] = __builtin_amdgcn_mfma_f32_16x16x32_bf16(af, bf, acc[j], 0, 0, 0);
        }
    }
    // C layout: row m = quad*4 + r, col n = j*16 + l15 -> stage in LDS
    #pragma unroll
    for (int j = 0; j < 8; ++j) {
        const float bias = bias2[blockIdx.y * 128 + j * 16 + l15];
        #pragma unroll
        for (int r = 0; r < 4; ++r)
            ct[wave][quad * 4 + r][j * 16 + l15] = bf16bits(acc[j][r] + bias);
    }
    // coalesced store: instr i covers rows [i*4, i*4+4), 16 lanes x 16B per row
    #pragma unroll
    for (int i = 0; i < 4; ++i) {
        const int row = i * 4 + (lane >> 4);
        uint4 v = *(const uint4*)&ct[wave][row][l15 * 8];
        *(uint4*)(xprojb + (size_t)(m0 + row) * N2 + blockIdx.y * 128 + l15 * 8) = v;
    }
}

// ---------------------------------------------------------------------------
// K2: BiLSTM, W register-resident, 8-way gate split, TAG-IN-DATA sync.
// 64 blocks x 256 threads. NEW: roles are ELECTED, not blockIdx-derived.
// Each block reads its XCD (HW_REG_XCC_ID), takes a per-XCD rank via a
// device-scope counter, soft grid-barriers (all 64 blocks are co-resident
// by construction — the kernel already spins on peer data), then claims
// (group = xcd, slice = rank) so a group's 8 blocks SHARE ONE XCD L2.
// Over-subscribed XCDs spill deterministically to leftover slots; those
// links simply run on the agent-scope fallback path.
// Exchange per h-pair: plain store -> hbufA (local-L2 coherent fast path,
// sc0 polls) + relaxed agent atomic -> hbufB (IC fallback). Tag+payload
// share one 8B word; parity-slot reuse safe (every block consumes ALL
// tag-t words before publishing t+1); cross-replay staleness closed by
// full-parity zeroing in k_prep.
// ---------------------------------------------------------------------------
__global__ __launch_bounds__(256, 1) void k_lstm_sync(
    const ushort_t* __restrict__ xprojb,   // (64,128,2048) bf16
    const float*    __restrict__ w_hh_f,   // (1024,256) f32
    const float*    __restrict__ w_hh_b,
    const int*      __restrict__ text_len,
    u64*            __restrict__ hbufB,    // [2][8][16][128] tagged words
    u64*            __restrict__ hbufA,    // same layout, L2 mirror
    unsigned*       __restrict__ ctl,      // election scratch
    float*          __restrict__ S)        // (64,512)
{
    __shared__ ushort_t hl[16][264];       // staged h bf16 [batch][k]
    __shared__ float    gLDS[4 * 16 * 33]; // [gate][batch][cell+pad]
    __shared__ int      roleS[2];

    const int tid   = threadIdx.x;

    // ---- one-time role election ----
    if (tid == 0) {
        unsigned xcd;
        asm volatile("s_getreg_b32 %0, hwreg(HW_REG_XCC_ID)" : "=s"(xcd));
        xcd &= 7u;
        const unsigned r = __hip_atomic_fetch_add(
            &ctl[xcd], 1u, __ATOMIC_RELAXED, __HIP_MEMORY_SCOPE_AGENT);
        __hip_atomic_fetch_add(&ctl[9], 1u, __ATOMIC_RELAXED,
                               __HIP_MEMORY_SCOPE_AGENT);
        while (__hip_atomic_load(&ctl[9], __ATOMIC_RELAXED,
                                 __HIP_MEMORY_SCOPE_AGENT) < 64u) {}
        unsigned slot;
        if (r < 8u) {
            slot = xcd * 8u + r;
        } else {
            const unsigned ov = __hip_atomic_fetch_add(
                &ctl[8], 1u, __ATOMIC_RELAXED, __HIP_MEMORY_SCOPE_AGENT);
            unsigned c = 0, found = 63;
            for (unsigned x = 0; x < 8u; ++x) {
                unsigned cnt = __hip_atomic_load(&ctl[x], __ATOMIC_RELAXED,
                                                 __HIP_MEMORY_SCOPE_AGENT);
                unsigned cap = cnt < 8u ? cnt : 8u;
                unsigned fre = 8u - cap;
                if (ov < c + fre) { found = x * 8u + cap + (ov - c); break; }
                c += fre;
            }
            slot = found;
        }
        roleS[0] = (int)(slot >> 3);   // group
        roleS[1] = (int)(slot & 7u);   // slice
    }
    __syncthreads();
    const int g     = roleS[0];
    const int slice = roleS[1];

    const int d     = g & 1;
    const int b0    = (g >> 1) * 16;
    const int j0    = slice * 32;
    const int wave  = tid >> 6, lane = tid & 63;
    const int quad  = lane >> 4, l15 = lane & 15;

    const float* whh = d ? w_hh_b : w_hh_f;
    u64* slabB0 = hbufB + (size_t)g * 2048;          // parity 0
    u64* slabB1 = hbufB + 16384 + (size_t)g * 2048;  // parity 1
    u64* slabA0 = hbufA + (size_t)g * 2048;
    u64* slabA1 = hbufA + 16384 + (size_t)g * 2048;

    // ---- preload W B-frags into registers (once) ----
    short8 wfrag[2][8];
    #pragma unroll
    for (int u = 0; u < 2; ++u) {
        const int n = wave * 256 + j0 + u * 16 + l15;
        #pragma unroll
        for (int ks = 0; ks < 8; ++ks) {
            const float* p = whh + (size_t)n * 256 + ks * 32 + quad * 8;
            float4 lo = *(const float4*)p;
            float4 hi = *(const float4*)(p + 4);
            short8 f;
            f[0] = (short)bf16bits(lo.x); f[1] = (short)bf16bits(lo.y);
            f[2] = (short)bf16bits(lo.z); f[3] = (short)bf16bits(lo.w);
            f[4] = (short)bf16bits(hi.x); f[5] = (short)bf16bits(hi.y);
            f[6] = (short)bf16bits(hi.z); f[7] = (short)bf16bits(hi.w);
            wfrag[u][ks] = f;
        }
    }

    // poll assignment: thread polls batch mb = tid>>4, words pp0..pp0+7
    // (pp0 = (tid&15)*8) -> all 8 words belong to ONE producer slice:
    // per-link sticky fallback is clean.
    // producer assignment: batch mb, cells c0,c0+1; word wi.
    const int mb  = tid >> 4;
    const int pp0 = (tid & 15) * 8;
    const int wi  = mb * 128 + slice * 16 + (tid & 15);
    const int c0  = (tid & 15) * 2;
    const int lenm = text_len[b0 + mb];
    float cst0 = 0.f, cst1 = 0.f, s0 = 0.f, s1 = 0.f;
    bool slow = false;   // sticky per-link fallback flag

    for (int t = 0; t < T_; ++t) {
        const int tt = d ? (T_ - 1 - t) : t;
        // prefetch xproj (bf16) — independent of h
        const ushort_t* xp = xprojb +
            ((size_t)(b0 + mb) * T_ + tt) * N2 + d * G4 + j0;
        const unsigned vi = *(const unsigned*)(xp + c0);
        const unsigned vf = *(const unsigned*)(xp + 256 + c0);
        const unsigned vg = *(const unsigned*)(xp + 512 + c0);
        const unsigned vo = *(const unsigned*)(xp + 768 + c0);

        // ---- poll own 8 tagged h words: A fast (local L2), B slow (IC) ----
        const u64* srcA = ((t & 1) ? slabA1 : slabA0) + mb * 128 + pp0;
        const u64* srcB = ((t & 1) ? slabB1 : slabB0) + mb * 128 + pp0;
        u64 v[8];
        bool need = true;
        if (!slow) {
            for (int tries = 0; tries < 48 && need; ++tries) {
                ld8_sc0(srcA, v);
                bool ok = true;
                #pragma unroll
                for (int i = 0; i < 8; ++i)
                    ok = ok && ((unsigned)(v[i] >> 32) == (unsigned)t);
                if (ok) need = false;
            }
            if (need) slow = true;   // link not L2-coherent -> agent path
        }
        if (need) {
            for (;;) {
                #pragma unroll
                for (int i = 0; i < 8; ++i)
                    v[i] = __hip_atomic_load(srcB + i, __ATOMIC_RELAXED,
                                             __HIP_MEMORY_SCOPE_AGENT);
                bool ok = true;
                #pragma unroll
                for (int i = 0; i < 8; ++i)
                    ok = ok && ((unsigned)(v[i] >> 32) == (unsigned)t);
                if (ok) break;
            }
        }
        // stage payload: 16 ushorts (32B) contiguous per thread
        {
            uint4 pk0, pk1;
            pk0.x = (unsigned)v[0]; pk0.y = (unsigned)v[1];
            pk0.z = (unsigned)v[2]; pk0.w = (unsigned)v[3];
            pk1.x = (unsigned)v[4]; pk1.y = (unsigned)v[5];
            pk1.z = (unsigned)v[6]; pk1.w = (unsigned)v[7];
            *(uint4*)&hl[mb][pp0 * 2]     = pk0;
            *(uint4*)&hl[mb][pp0 * 2 + 8] = pk1;
        }
        __syncthreads();   // B1: hl ready; also fences gLDS reuse

        // ---- all waves: A-frags from LDS, MFMA ----
        short8 af[8];
        #pragma unroll
        for (int ks = 0; ks < 8; ++ks)
            af[ks] = *(const short8*)&hl[l15][ks * 32 + quad * 8];
        f32x4 acc[2] = {};
        #pragma unroll
        for (int ks = 0; ks < 8; ++ks) {
            acc[0] = __builtin_amdgcn_mfma_f32_16x16x32_bf16(
                af[ks], wfrag[0][ks], acc[0], 0, 0, 0);
            acc[1] = __builtin_amdgcn_mfma_f32_16x16x32_bf16(
                af[ks], wfrag[1][ks], acc[1], 0, 0, 0);
        }
        // C layout: row(batch)=quad*4+r, col=l15
        #pragma unroll
        for (int u = 0; u < 2; ++u)
            #pragma unroll
            for (int r = 0; r < 4; ++r)
                gLDS[wave * 528 + (quad * 4 + r) * 33 + u * 16 + l15] = acc[u][r];
        __syncthreads();   // B2: gates ready; also fences hl reuse

        // ---- cell update for (mb, c0..c0+1) ----
        const int gb = mb * 33 + c0;
        const float gi0 = gLDS[gb],        gi1 = gLDS[gb + 1];
        const float gf0 = gLDS[528 + gb],  gf1 = gLDS[528 + gb + 1];
        const float gg0 = gLDS[1056 + gb], gg1 = gLDS[1056 + gb + 1];
        const float go0 = gLDS[1584 + gb], go1 = gLDS[1584 + gb + 1];
        const float i0 = sigm_f(bf16lo(vi) + gi0);
        const float i1 = sigm_f(bf16hi(vi) + gi1);
        const float f0 = sigm_f(bf16lo(vf) + gf0);
        const float f1 = sigm_f(bf16hi(vf) + gf1);
        const float gc0 = tanh_f(bf16lo(vg) + gg0);
        const float gc1 = tanh_f(bf16hi(vg) + gg1);
        const float o0 = sigm_f(bf16lo(vo) + go0);
        const float o1 = sigm_f(bf16hi(vo) + go1);
        cst0 = f0 * cst0 + i0 * gc0;
        cst1 = f1 * cst1 + i1 * gc1;
        const float h0 = o0 * tanh_f(cst0);
        const float h1 = o1 * tanh_f(cst1);
        if (tt < lenm) { s0 += h0; s1 += h1; }

        // publish h_{t+1}: tag+payload in ONE 8B word, double-published.
        const u64 word = ((u64)(unsigned)(t + 1) << 32) |
                         (u64)((unsigned)bf16bits(h0) |
                               ((unsigned)bf16bits(h1) << 16));
        u64* dstA = ((t & 1) ? slabA0 : slabA1) + wi;
        u64* dstB = ((t & 1) ? slabB0 : slabB1) + wi;
        *(volatile u64*)dstA = word;            // plain -> XCD L2 (fast path)
        __hip_atomic_store(dstB, word, __ATOMIC_RELAXED,
                           __HIP_MEMORY_SCOPE_AGENT);  // IC (fallback path)
    }

    float2 sv; sv.x = s0; sv.y = s1;
    *(float2*)(S + (size_t)(b0 + mb) * GG + d * H_ + j0 + c0) = sv;
}

// ---------------------------------------------------------------------------
// K3: head (unchanged).
// ---------------------------------------------------------------------------
__global__ __launch_bounds__(256) void k_head(
    const float* __restrict__ S,
    const int*   __restrict__ text_len,
    const float* __restrict__ gat_w, const float* __restrict__ gat_b,
    const float* __restrict__ fc1_w, const float* __restrict__ fc1_b,
    const float* __restrict__ fc2_w, const float* __restrict__ fc2_b,
    const float* __restrict__ fcf_w, const float* __restrict__ fcf_b,
    float* __restrict__ out)
{
    __shared__ float sb[GG];
    __shared__ float x1[GG];
    __shared__ float x2[FH_];
    __shared__ float x3[FH_];
    const int b = blockIdx.x, tid = threadIdx.x;
    sb[tid]       = S[(size_t)b * GG + tid];
    sb[tid + 256] = S[(size_t)b * GG + tid + 256];
    __syncthreads();
    const float lenf = (float)text_len[b];
    #pragma unroll
    for (int r = 0; r < 2; ++r) {
        const int n = tid + r * 256;
        float acc = gat_b[n] * lenf;
        const float* w = gat_w + (size_t)n * GG;
        for (int k = 0; k < GG; ++k) acc += sb[k] * w[k];
        x1[n] = fmaxf(acc, 0.f);
    }
    __syncthreads();
    {
        float acc = fc1_b[tid];
        const float* w = fc1_w + (size_t)tid * GG;
        for (int k = 0; k < GG; ++k) acc += x1[k] * w[k];
        x2[tid] = fmaxf(acc, 0.f);
    }
    __syncthreads();
    {
        float acc = fc2_b[tid];
        const float* w = fc2_w + (size_t)tid * FH_;
        for (int k = 0; k < FH_; ++k) acc += x2[k] * w[k];
        x3[tid] = fmaxf(acc, 0.f);
    }
    __syncthreads();
    if (tid < NC_) {
        float acc = fcf_b[tid];
        const float* w = fcf_w + (size_t)tid * FH_;
        for (int k = 0; k < FH_; ++k) acc += x3[k] * w[k];
        out[b * NC_ + tid] = acc;
    }
}

// ---------------------------------------------------------------------------
extern "C" void kernel_launch(void* const* d_in, const int* in_sizes, int n_in,
                              void* d_out, int out_size, void* d_ws, size_t ws_size,
                              hipStream_t stream) {
    const int*   sentence = (const int*)  d_in[0];
    const int*   text_len = (const int*)  d_in[4];
    const float* glove    = (const float*)d_in[10];
    const float* w_ih_f   = (const float*)d_in[11];
    const float* w_hh_f   = (const float*)d_in[12];
    const float* b_ih_f   = (const float*)d_in[13];
    const float* b_hh_f   = (const float*)d_in[14];
    const float* w_ih_b   = (const float*)d_in[15];
    const float* w_hh_b   = (const float*)d_in[16];
    const float* b_ih_b   = (const float*)d_in[17];
    const float* b_hh_b   = (const float*)d_in[18];
    const float* gat_w    = (const float*)d_in[19];
    const float* gat_b    = (const float*)d_in[20];
    const float* fc1_w    = (const float*)d_in[21];
    const float* fc1_b    = (const float*)d_in[22];
    const float* fc2_w    = (const float*)d_in[23];
    const float* fc2_b    = (const float*)d_in[24];
    const float* fcf_w    = (const float*)d_in[25];
    const float* fcf_b    = (const float*)d_in[26];
    float* out = (float*)d_out;

    char* ws = (char*)d_ws;
    u64*      hbufB   = (u64*)ws;
    float*    bias2   = (float*)(ws + OFF_BIAS);
    unsigned* ctl     = (unsigned*)(ws + OFF_CTL);
    ushort_t* wihshuf = (ushort_t*)(ws + OFF_WIH);
    u64*      hbufA   = (u64*)(ws + OFF_A);
    ushort_t* xemb    = (ushort_t*)(ws + OFF_XEMB);
    ushort_t* xprojb  = (ushort_t*)(ws + OFF_XPROJ);
    float*    S       = (float*)(ws + OFF_S);

    k_prep<<<2560, 256, 0, stream>>>(sentence, glove, w_ih_f, w_ih_b,
                                     b_ih_f, b_hh_f, b_ih_b, b_hh_b,
                                     hbufB, hbufA, ctl, bias2, wihshuf, xemb);
    dim3 gx(128, 16);
    k_xproj_mfma<<<gx, 256, 0, stream>>>(xemb, wihshuf, bias2, xprojb);
    k_lstm_sync<<<64, 256, 0, stream>>>(xprojb, w_hh_f, w_hh_b, text_len,
                                        hbufB, hbufA, ctl, S);
    k_head<<<64, 256, 0, stream>>>(S, text_len, gat_w, gat_b,
                                   fc1_w, fc1_b, fc2_w, fc2_b,
                                   fcf_w, fcf_b, out);
}